// Round 3
// baseline (606.724 us; speedup 1.0000x reference)
//
#include <hip/hip_runtime.h>

typedef float f32x16 __attribute__((ext_vector_type(16)));
typedef float f32x4  __attribute__((ext_vector_type(4)));
typedef short s16x8  __attribute__((ext_vector_type(8)));
typedef short s16x4  __attribute__((ext_vector_type(4)));

constexpr int Bn = 2, Tn = 2048, Dn = 768, Hn = 12, DHn = 64;
constexpr int NX = Bn * Tn * Dn;   // 3,145,728 (= B*T*D = B*H*T*Dh)
constexpr int NW = Dn * Dn;        // 589,824
constexpr float SC2f = 0.125f * 1.44269504088896f;  // (1/sqrt(64))*log2(e)

__device__ __forceinline__ unsigned short f2bf(float f) {
    union { float f; unsigned int i; } c; c.f = f;
    unsigned int u = c.i;
    u += 0x7fffu + ((u >> 16) & 1u);
    return (unsigned short)(u >> 16);
}
__device__ __forceinline__ s16x8 comb(s16x4 lo, s16x4 hi) {
    s16x8 r;
    r[0]=lo[0]; r[1]=lo[1]; r[2]=lo[2]; r[3]=lo[3];
    r[4]=hi[0]; r[5]=hi[1]; r[6]=hi[2]; r[7]=hi[3];
    return r;
}

// ---- f32 -> bf16 one-shot conversion of x, Wq, Wk, Wv into ws ----
__global__ __launch_bounds__(256) void cvt_bf16(
    const float* __restrict__ x,  const float* __restrict__ wq,
    const float* __restrict__ wk, const float* __restrict__ wv,
    unsigned short* __restrict__ out)
{
    const long i8 = ((long)blockIdx.x * 256 + threadIdx.x) * 8;
    const float* src;
    if (i8 < NX)               src = x  + i8;
    else if (i8 < NX + NW)     src = wq + (i8 - NX);
    else if (i8 < NX + 2*NW)   src = wk + (i8 - NX - 2l*NW + NW);
    else                       src = wv + (i8 - NX - 2l*NW);
    f32x4 a = *(const f32x4*)src;
    f32x4 b = *(const f32x4*)(src + 4);
    s16x8 r;
    r[0]=(short)f2bf(a[0]); r[1]=(short)f2bf(a[1]);
    r[2]=(short)f2bf(a[2]); r[3]=(short)f2bf(a[3]);
    r[4]=(short)f2bf(b[0]); r[5]=(short)f2bf(b[1]);
    r[6]=(short)f2bf(b[2]); r[7]=(short)f2bf(b[3]);
    *(s16x8*)(out + i8) = r;
}

// ---- fused QKV projection (bf16 GEMM, z picks Q/K/V) ----
// z=0: Q = (x Wq^T + bq)*SC2 -> [BH][T][Dh]; z=1: K -> same layout;
// z=2: V^T -> [BH][Dh][T].
__global__ __launch_bounds__(256) void proj_kernel(
    const unsigned short* __restrict__ xbf,
    const unsigned short* __restrict__ wbf,   // [3][NW]
    const float* __restrict__ bq, const float* __restrict__ bk,
    const float* __restrict__ bv,
    unsigned short* __restrict__ qo, unsigned short* __restrict__ ko,
    unsigned short* __restrict__ vo)
{
    const int z = blockIdx.z;
    const unsigned short* W = wbf + (size_t)z * NW;
    const float* bias = (z == 0) ? bq : (z == 1) ? bk : bv;
    const int tid = threadIdx.x, lane = tid & 63, wid = tid >> 6;
    const int lq = lane & 31, g = lane >> 5;
    const bool vt = (z == 2);
    const int mb = vt ? blockIdx.y : blockIdx.x;
    const int nb = vt ? blockIdx.x : blockIdx.y;
    const int mbase = mb * 64 + (wid & 1) * 32;
    const int nbase = nb * 64 + (wid >> 1) * 32;
    const unsigned short* A  = vt ? W : xbf;
    const unsigned short* Bm = vt ? xbf : W;
    const unsigned short* arow = A  + (size_t)(mbase + lq) * Dn + g * 8;
    const unsigned short* brow = Bm + (size_t)(nbase + lq) * Dn + g * 8;

    f32x16 acc;
#pragma unroll
    for (int i = 0; i < 16; ++i) acc[i] = 0.f;
#pragma unroll 4
    for (int c = 0; c < 48; ++c) {
        s16x8 af = *(const s16x8*)(arow + c * 16);
        s16x8 bf = *(const s16x8*)(brow + c * 16);
        acc = __builtin_amdgcn_mfma_f32_32x32x16_bf16(af, bf, acc, 0, 0, 0);
    }

    if (!vt) {
        unsigned short* out = (z == 0) ? qo : ko;
        const float scale = (z == 0) ? SC2f : 1.f;
        const int e = nbase + lq;
        const float bvl = bias[e];
        const int h = e >> 6, dh = e & 63;
#pragma unroll
        for (int r = 0; r < 16; ++r) {
            const int t = mbase + ((r & 3) + 8 * (r >> 2) + 4 * g);
            const int b = t >> 11, tl = t & (Tn - 1);
            out[((size_t)(b * Hn + h) * Tn + tl) * DHn + dh] = f2bf((acc[r] + bvl) * scale);
        }
    } else {
        const int t = nbase + lq;
        const int b = t >> 11, tl = t & (Tn - 1);
#pragma unroll
        for (int r = 0; r < 16; ++r) {
            const int e = mbase + ((r & 3) + 8 * (r >> 2) + 4 * g);
            const float bvl = bias[e];
            const int h = e >> 6, dh = e & 63;
            vo[((size_t)(b * Hn + h) * DHn + dh) * Tn + tl] = f2bf(acc[r] + bvl);
        }
    }
}

// Block decode shared by both attn passes:
// 768 blocks -> XCD-chunked (3 heads/XCD); block = strips {u, 63-u},
// each strip split into 2 k-chunks (4 waves total).
#define ATTN_DECODE()                                                   \
    const int tid = threadIdx.x, lane = tid & 63, wid = tid >> 6;       \
    const int lq = lane & 31, g = lane >> 5;                            \
    const int n2 = ((int)blockIdx.x & 7) * 96 + ((int)blockIdx.x >> 3); \
    const int bh = n2 >> 5;                                             \
    const int u  = n2 & 31;                                             \
    const int s  = (wid & 2) ? (63 - u) : u;                            \
    const int cc = wid & 1;                                             \
    const int qbase = s * 32;                                           \
    const int h2 = (s + 1) >> 1;                                        \
    const int k0 = cc ? h2 : 0;                                         \
    const int kend = cc ? s : h2;   /* maskless range; cc owns diag s */

// ---- pass 1: l[row] = sum_k exp2(q.k) via per-chunk partials + atomics ----
__global__ __launch_bounds__(256) void attn_pass1(
    const unsigned short* __restrict__ Q,   // pre-scaled by SC2
    const unsigned short* __restrict__ K,
    float* __restrict__ lsum)               // [BH][T], pre-zeroed
{
    ATTN_DECODE();
    const unsigned short* Qb = Q + ((size_t)bh * Tn + qbase) * DHn;
    const unsigned short* Kb = K + (size_t)bh * Tn * DHn;

    s16x8 qf[4];
#pragma unroll
    for (int c = 0; c < 4; ++c)
        qf[c] = *(const s16x8*)(Qb + lq * DHn + c * 16 + g * 8);

    float ls = 0.f;
    for (int kt = k0; kt < kend; ++kt) {
        const unsigned short* krow = Kb + (size_t)(kt * 32 + lq) * DHn + g * 8;
        f32x16 acc;
#pragma unroll
        for (int i = 0; i < 16; ++i) acc[i] = 0.f;
#pragma unroll
        for (int c = 0; c < 4; ++c)
            acc = __builtin_amdgcn_mfma_f32_32x32x16_bf16(
                *(const s16x8*)(krow + c * 16), qf[c], acc, 0, 0, 0);
#pragma unroll
        for (int r = 0; r < 16; ++r) ls += exp2f(acc[r]);
    }
    if (cc) {  // diagonal tile s, causal-masked
        const unsigned short* krow = Kb + (size_t)(s * 32 + lq) * DHn + g * 8;
        f32x16 acc;
#pragma unroll
        for (int i = 0; i < 16; ++i) acc[i] = 0.f;
#pragma unroll
        for (int c = 0; c < 4; ++c)
            acc = __builtin_amdgcn_mfma_f32_32x32x16_bf16(
                *(const s16x8*)(krow + c * 16), qf[c], acc, 0, 0, 0);
#pragma unroll
        for (int r = 0; r < 16; ++r) {
            const int koff = (r & 3) + 8 * (r >> 2) + 4 * g;
            ls += (koff <= lq) ? exp2f(acc[r]) : 0.f;
        }
    }
    atomicAdd(&lsum[(size_t)bh * Tn + qbase + lq], ls);
}

// ---- pass 2: P = exp2(q.k)/l -> attn (+ fused upper-zero fill), O = P.V ----
__global__ __launch_bounds__(256) void attn_pass2(
    const unsigned short* __restrict__ Q,
    const unsigned short* __restrict__ K,
    const unsigned short* __restrict__ Vt,  // [BH][Dh][T]
    const float* __restrict__ lsum,
    float* __restrict__ heads,              // [B][T][H][Dh]
    float* __restrict__ attn)               // [BH][T][T]
{
    __shared__ float olds[2][32][64];
    ATTN_DECODE();
    const int slot = wid >> 1;
    const unsigned short* Qb = Q  + ((size_t)bh * Tn + qbase) * DHn;
    const unsigned short* Kb = K  + (size_t)bh * Tn * DHn;
    const unsigned short* Vb = Vt + (size_t)bh * DHn * Tn;
    const float rl = 1.f / lsum[(size_t)bh * Tn + qbase + lq];
    const size_t arow0 = ((size_t)bh * Tn + (qbase + lq)) * Tn;

    s16x8 qf[4];
#pragma unroll
    for (int c = 0; c < 4; ++c)
        qf[c] = *(const s16x8*)(Qb + lq * DHn + c * 16 + g * 8);

    f32x16 o0, o1;
#pragma unroll
    for (int i = 0; i < 16; ++i) { o0[i] = 0.f; o1[i] = 0.f; }

    for (int kt = k0; kt <= kend; ++kt) {        // kend inclusive only for cc (diag)
        if (kt == kend && !cc) break;
        const bool diag = (kt == s);
        const unsigned short* krow = Kb + (size_t)(kt * 32 + lq) * DHn + g * 8;
        f32x16 acc;
#pragma unroll
        for (int i = 0; i < 16; ++i) acc[i] = 0.f;
#pragma unroll
        for (int c = 0; c < 4; ++c)
            acc = __builtin_amdgcn_mfma_f32_32x32x16_bf16(
                *(const s16x8*)(krow + c * 16), qf[c], acc, 0, 0, 0);

        float pv[16];
#pragma unroll
        for (int r = 0; r < 16; ++r) {
            const int koff = (r & 3) + 8 * (r >> 2) + 4 * g;
            float e = exp2f(acc[r]) * rl;
            pv[r] = (diag && koff > lq) ? 0.f : e;
        }

        float* ar = attn + arow0 + kt * 32 + 4 * g;
#pragma unroll
        for (int a = 0; a < 4; ++a) {
            f32x4 w;
            w[0]=pv[4*a+0]; w[1]=pv[4*a+1]; w[2]=pv[4*a+2]; w[3]=pv[4*a+3];
            __builtin_nontemporal_store(w, (f32x4*)(ar + 8 * a));
        }

        s16x8 pa0, pa1;
#pragma unroll
        for (int j = 0; j < 8; ++j) {
            pa0[j] = (short)f2bf(pv[j]);
            pa1[j] = (short)f2bf(pv[8 + j]);
        }
        const unsigned short* vr0 = Vb + (size_t)lq * Tn + kt * 32;
        const unsigned short* vr1 = Vb + (size_t)(32 + lq) * Tn + kt * 32;
#pragma unroll
        for (int c2 = 0; c2 < 2; ++c2) {
            const s16x8 pa = c2 ? pa1 : pa0;
            s16x4 lo0 = *(const s16x4*)(vr0 + c2 * 16 + 4 * g);
            s16x4 hi0 = *(const s16x4*)(vr0 + c2 * 16 + 8 + 4 * g);
            o0 = __builtin_amdgcn_mfma_f32_32x32x16_bf16(pa, comb(lo0, hi0), o0, 0, 0, 0);
            s16x4 lo1 = *(const s16x4*)(vr1 + c2 * 16 + 4 * g);
            s16x4 hi1 = *(const s16x4*)(vr1 + c2 * 16 + 8 + 4 * g);
            o1 = __builtin_amdgcn_mfma_f32_32x32x16_bf16(pa, comb(lo1, hi1), o1, 0, 0, 0);
        }
    }

    // pooled zero-fill of the strictly-upper region for both strips
    {
        const int nzu = 63 - u;                  // zeros of strip u; strip 63-u has u
        f32x4 z; z[0]=0.f; z[1]=0.f; z[2]=0.f; z[3]=0.f;
        for (int j = wid; j < 63; j += 4) {
            int zs, zkt;
            if (j < nzu) { zs = u;      zkt = u + 1 + j; }
            else         { zs = 63 - u; zkt = (63 - u) + 1 + (j - nzu); }
            float* ar = attn + ((size_t)bh * Tn + zs * 32 + lq) * Tn + zkt * 32 + 4 * g;
#pragma unroll
            for (int a = 0; a < 4; ++a)
                __builtin_nontemporal_store(z, (f32x4*)(ar + 8 * a));
        }
    }

    // combine the two k-chunks' O via LDS; cc==1 writes heads
    if (!cc) {
#pragma unroll
        for (int r = 0; r < 16; ++r) {
            const int tr = (r & 3) + 8 * (r >> 2) + 4 * g;
            olds[slot][tr][lq]      = o0[r];
            olds[slot][tr][32 + lq] = o1[r];
        }
    }
    __syncthreads();
    if (cc) {
        const int b = bh / Hn, hh = bh % Hn;
#pragma unroll
        for (int r = 0; r < 16; ++r) {
            const int tr = (r & 3) + 8 * (r >> 2) + 4 * g;
            const int t = qbase + tr;
            float* base = heads + ((size_t)(b * Tn + t)) * Dn + hh * DHn;
            base[lq]      = o0[r] + olds[slot][tr][lq];
            base[32 + lq] = o1[r] + olds[slot][tr][32 + lq];
        }
    }
}

extern "C" void kernel_launch(void* const* d_in, const int* in_sizes, int n_in,
                              void* d_out, int out_size, void* d_ws, size_t ws_size,
                              hipStream_t stream) {
    (void)in_sizes; (void)n_in; (void)out_size; (void)ws_size;
    const float* x  = (const float*)d_in[0];
    const float* Wq = (const float*)d_in[1];
    const float* bq = (const float*)d_in[2];
    const float* Wk = (const float*)d_in[3];
    const float* bk = (const float*)d_in[4];
    const float* Wv = (const float*)d_in[5];
    const float* bv = (const float*)d_in[6];
    // d_in[7] = attn_mask: structurally causal, handled in-kernel.

    float* heads = (float*)d_out;
    float* attn  = heads + (size_t)Bn * Tn * Dn;

    unsigned short* xbf  = (unsigned short*)d_ws;   // [NX] then [3][NW] weights
    unsigned short* qws  = xbf + NX + 3 * (size_t)NW;
    unsigned short* kws  = qws + NX;
    unsigned short* vtws = kws + NX;
    float* lsum = (float*)(vtws + NX);              // [BH][T]

    hipMemsetAsync(lsum, 0, (size_t)Bn * Hn * Tn * sizeof(float), stream);
    cvt_bf16<<<(NX + 3 * NW) / (256 * 8), 256, 0, stream>>>(x, Wq, Wk, Wv, xbf);
    proj_kernel<<<dim3(64, 12, 3), 256, 0, stream>>>(xbf, xbf + NX, bq, bk, bv,
                                                     qws, kws, vtws);
    attn_pass1<<<768, 256, 0, stream>>>(qws, kws, lsum);
    attn_pass2<<<768, 256, 0, stream>>>(qws, kws, vtws, lsum, heads, attn);
}

// Round 4
// 310.765 us; speedup vs baseline: 1.9524x; 1.9524x over previous
//
#include <hip/hip_runtime.h>

typedef float f32x16 __attribute__((ext_vector_type(16)));
typedef float f32x4  __attribute__((ext_vector_type(4)));
typedef short s16x8  __attribute__((ext_vector_type(8)));
typedef short s16x4  __attribute__((ext_vector_type(4)));

constexpr int Bn = 2, Tn = 2048, Dn = 768, Hn = 12, DHn = 64;
constexpr int NX = Bn * Tn * Dn;   // 3,145,728 (= B*T*D = B*H*T*Dh)
constexpr int NW = Dn * Dn;        // 589,824
constexpr float SC2f = 0.125f * 1.44269504088896f;  // (1/sqrt(64))*log2(e)

__device__ __forceinline__ unsigned short f2bf(float f) {
    union { float f; unsigned int i; } c; c.f = f;
    unsigned int u = c.i;
    u += 0x7fffu + ((u >> 16) & 1u);
    return (unsigned short)(u >> 16);
}
__device__ __forceinline__ s16x8 comb(s16x4 lo, s16x4 hi) {
    s16x8 r;
    r[0]=lo[0]; r[1]=lo[1]; r[2]=lo[2]; r[3]=lo[3];
    r[4]=hi[0]; r[5]=hi[1]; r[6]=hi[2]; r[7]=hi[3];
    return r;
}

// ---- f32 -> bf16 one-shot conversion of x, Wq, Wk, Wv into ws ----
__global__ __launch_bounds__(256) void cvt_bf16(
    const float* __restrict__ x,  const float* __restrict__ wq,
    const float* __restrict__ wk, const float* __restrict__ wv,
    unsigned short* __restrict__ out)
{
    const long i8 = ((long)blockIdx.x * 256 + threadIdx.x) * 8;
    const float* src;
    if (i8 < NX)               src = x  + i8;
    else if (i8 < NX + NW)     src = wq + (i8 - NX);
    else if (i8 < NX + 2*NW)   src = wk + (i8 - NX - 2l*NW + NW);
    else                       src = wv + (i8 - NX - 2l*NW);
    f32x4 a = *(const f32x4*)src;
    f32x4 b = *(const f32x4*)(src + 4);
    s16x8 r;
    r[0]=(short)f2bf(a[0]); r[1]=(short)f2bf(a[1]);
    r[2]=(short)f2bf(a[2]); r[3]=(short)f2bf(a[3]);
    r[4]=(short)f2bf(b[0]); r[5]=(short)f2bf(b[1]);
    r[6]=(short)f2bf(b[2]); r[7]=(short)f2bf(b[3]);
    *(s16x8*)(out + i8) = r;
}

// ---- fused QKV projection (bf16 GEMM, z picks Q/K/V) ----
// z=0: Q = (x Wq^T + bq)*SC2 -> [BH][T][Dh]; z=1: K -> same layout;
// z=2: V^T -> [BH][Dh][T].
__global__ __launch_bounds__(256) void proj_kernel(
    const unsigned short* __restrict__ xbf,
    const unsigned short* __restrict__ wbf,   // [3][NW]
    const float* __restrict__ bq, const float* __restrict__ bk,
    const float* __restrict__ bv,
    unsigned short* __restrict__ qo, unsigned short* __restrict__ ko,
    unsigned short* __restrict__ vo)
{
    const int z = blockIdx.z;
    const unsigned short* W = wbf + (size_t)z * NW;
    const float* bias = (z == 0) ? bq : (z == 1) ? bk : bv;
    const int tid = threadIdx.x, lane = tid & 63, wid = tid >> 6;
    const int lq = lane & 31, g = lane >> 5;
    const bool vt = (z == 2);
    const int mb = vt ? blockIdx.y : blockIdx.x;
    const int nb = vt ? blockIdx.x : blockIdx.y;
    const int mbase = mb * 64 + (wid & 1) * 32;
    const int nbase = nb * 64 + (wid >> 1) * 32;
    const unsigned short* A  = vt ? W : xbf;
    const unsigned short* Bm = vt ? xbf : W;
    const unsigned short* arow = A  + (size_t)(mbase + lq) * Dn + g * 8;
    const unsigned short* brow = Bm + (size_t)(nbase + lq) * Dn + g * 8;

    f32x16 acc;
#pragma unroll
    for (int i = 0; i < 16; ++i) acc[i] = 0.f;
#pragma unroll 4
    for (int c = 0; c < 48; ++c) {
        s16x8 af = *(const s16x8*)(arow + c * 16);
        s16x8 bf = *(const s16x8*)(brow + c * 16);
        acc = __builtin_amdgcn_mfma_f32_32x32x16_bf16(af, bf, acc, 0, 0, 0);
    }

    if (!vt) {
        unsigned short* out = (z == 0) ? qo : ko;
        const float scale = (z == 0) ? SC2f : 1.f;
        const int e = nbase + lq;
        const float bvl = bias[e];
        const int h = e >> 6, dh = e & 63;
#pragma unroll
        for (int r = 0; r < 16; ++r) {
            const int t = mbase + ((r & 3) + 8 * (r >> 2) + 4 * g);
            const int b = t >> 11, tl = t & (Tn - 1);
            out[((size_t)(b * Hn + h) * Tn + tl) * DHn + dh] = f2bf((acc[r] + bvl) * scale);
        }
    } else {
        const int t = nbase + lq;
        const int b = t >> 11, tl = t & (Tn - 1);
#pragma unroll
        for (int r = 0; r < 16; ++r) {
            const int e = mbase + ((r & 3) + 8 * (r >> 2) + 4 * g);
            const float bvl = bias[e];
            const int h = e >> 6, dh = e & 63;
            vo[((size_t)(b * Hn + h) * DHn + dh) * Tn + tl] = f2bf(acc[r] + bvl);
        }
    }
}

// Block decode shared by both attn passes:
// 768 blocks -> XCD-chunked (3 heads/XCD); block = strips {u, 63-u},
// each strip split into 2 k-chunks (4 waves total).
#define ATTN_DECODE()                                                   \
    const int tid = threadIdx.x, lane = tid & 63, wid = tid >> 6;       \
    const int lq = lane & 31, g = lane >> 5;                            \
    const int n2 = ((int)blockIdx.x & 7) * 96 + ((int)blockIdx.x >> 3); \
    const int bh = n2 >> 5;                                             \
    const int u  = n2 & 31;                                             \
    const int s  = (wid & 2) ? (63 - u) : u;                            \
    const int cc = wid & 1;                                             \
    const int qbase = s * 32;                                           \
    const int h2 = (s + 1) >> 1;                                        \
    const int k0 = cc ? h2 : 0;                                         \
    const int kend = cc ? s : h2;   /* maskless range; cc owns diag s */

// ---- pass 1: l[row] = sum_k exp2(q.k) via per-chunk partials + atomics ----
__global__ __launch_bounds__(256) void attn_pass1(
    const unsigned short* __restrict__ Q,   // pre-scaled by SC2
    const unsigned short* __restrict__ K,
    float* __restrict__ lsum)               // [BH][T], pre-zeroed
{
    ATTN_DECODE();
    const unsigned short* Qb = Q + ((size_t)bh * Tn + qbase) * DHn;
    const unsigned short* Kb = K + (size_t)bh * Tn * DHn;

    s16x8 qf[4];
#pragma unroll
    for (int c = 0; c < 4; ++c)
        qf[c] = *(const s16x8*)(Qb + lq * DHn + c * 16 + g * 8);

    float ls = 0.f;
    for (int kt = k0; kt < kend; ++kt) {
        const unsigned short* krow = Kb + (size_t)(kt * 32 + lq) * DHn + g * 8;
        f32x16 acc;
#pragma unroll
        for (int i = 0; i < 16; ++i) acc[i] = 0.f;
#pragma unroll
        for (int c = 0; c < 4; ++c)
            acc = __builtin_amdgcn_mfma_f32_32x32x16_bf16(
                *(const s16x8*)(krow + c * 16), qf[c], acc, 0, 0, 0);
#pragma unroll
        for (int r = 0; r < 16; ++r) ls += exp2f(acc[r]);
    }
    if (cc) {  // diagonal tile s, causal-masked
        const unsigned short* krow = Kb + (size_t)(s * 32 + lq) * DHn + g * 8;
        f32x16 acc;
#pragma unroll
        for (int i = 0; i < 16; ++i) acc[i] = 0.f;
#pragma unroll
        for (int c = 0; c < 4; ++c)
            acc = __builtin_amdgcn_mfma_f32_32x32x16_bf16(
                *(const s16x8*)(krow + c * 16), qf[c], acc, 0, 0, 0);
#pragma unroll
        for (int r = 0; r < 16; ++r) {
            const int koff = (r & 3) + 8 * (r >> 2) + 4 * g;
            ls += (koff <= lq) ? exp2f(acc[r]) : 0.f;
        }
    }
    atomicAdd(&lsum[(size_t)bh * Tn + qbase + lq], ls);
}

// ---- pass 2: P = exp2(q.k)/l -> attn (+ fused upper-zero fill), O = P.V ----
__global__ __launch_bounds__(256) void attn_pass2(
    const unsigned short* __restrict__ Q,
    const unsigned short* __restrict__ K,
    const unsigned short* __restrict__ Vt,  // [BH][Dh][T]
    const float* __restrict__ lsum,
    float* __restrict__ heads,              // [B][T][H][Dh]
    float* __restrict__ attn)               // [BH][T][T]
{
    __shared__ float olds[2][32][64];
    ATTN_DECODE();
    const int slot = wid >> 1;
    const unsigned short* Qb = Q  + ((size_t)bh * Tn + qbase) * DHn;
    const unsigned short* Kb = K  + (size_t)bh * Tn * DHn;
    const unsigned short* Vb = Vt + (size_t)bh * DHn * Tn;
    const float rl = 1.f / lsum[(size_t)bh * Tn + qbase + lq];
    const size_t arow0 = ((size_t)bh * Tn + (qbase + lq)) * Tn;

    s16x8 qf[4];
#pragma unroll
    for (int c = 0; c < 4; ++c)
        qf[c] = *(const s16x8*)(Qb + lq * DHn + c * 16 + g * 8);

    f32x16 o0, o1;
#pragma unroll
    for (int i = 0; i < 16; ++i) { o0[i] = 0.f; o1[i] = 0.f; }

    for (int kt = k0; kt <= kend; ++kt) {        // kend inclusive only for cc (diag)
        if (kt == kend && !cc) break;
        const bool diag = (kt == s);
        const unsigned short* krow = Kb + (size_t)(kt * 32 + lq) * DHn + g * 8;
        f32x16 acc;
#pragma unroll
        for (int i = 0; i < 16; ++i) acc[i] = 0.f;
#pragma unroll
        for (int c = 0; c < 4; ++c)
            acc = __builtin_amdgcn_mfma_f32_32x32x16_bf16(
                *(const s16x8*)(krow + c * 16), qf[c], acc, 0, 0, 0);

        float pv[16];
#pragma unroll
        for (int r = 0; r < 16; ++r) {
            const int koff = (r & 3) + 8 * (r >> 2) + 4 * g;
            float e = exp2f(acc[r]) * rl;
            pv[r] = (diag && koff > lq) ? 0.f : e;
        }

        float* ar = attn + arow0 + kt * 32 + 4 * g;
#pragma unroll
        for (int a = 0; a < 4; ++a) {
            f32x4 w;
            w[0]=pv[4*a+0]; w[1]=pv[4*a+1]; w[2]=pv[4*a+2]; w[3]=pv[4*a+3];
            *(f32x4*)(ar + 8 * a) = w;
        }

        s16x8 pa0, pa1;
#pragma unroll
        for (int j = 0; j < 8; ++j) {
            pa0[j] = (short)f2bf(pv[j]);
            pa1[j] = (short)f2bf(pv[8 + j]);
        }
        const unsigned short* vr0 = Vb + (size_t)lq * Tn + kt * 32;
        const unsigned short* vr1 = Vb + (size_t)(32 + lq) * Tn + kt * 32;
#pragma unroll
        for (int c2 = 0; c2 < 2; ++c2) {
            const s16x8 pa = c2 ? pa1 : pa0;
            s16x4 lo0 = *(const s16x4*)(vr0 + c2 * 16 + 4 * g);
            s16x4 hi0 = *(const s16x4*)(vr0 + c2 * 16 + 8 + 4 * g);
            o0 = __builtin_amdgcn_mfma_f32_32x32x16_bf16(pa, comb(lo0, hi0), o0, 0, 0, 0);
            s16x4 lo1 = *(const s16x4*)(vr1 + c2 * 16 + 4 * g);
            s16x4 hi1 = *(const s16x4*)(vr1 + c2 * 16 + 8 + 4 * g);
            o1 = __builtin_amdgcn_mfma_f32_32x32x16_bf16(pa, comb(lo1, hi1), o1, 0, 0, 0);
        }
    }

    // pooled zero-fill of the strictly-upper region for both strips
    {
        const int nzu = 63 - u;                  // zeros of strip u; strip 63-u has u
        f32x4 z; z[0]=0.f; z[1]=0.f; z[2]=0.f; z[3]=0.f;
        for (int j = wid; j < 63; j += 4) {
            int zs, zkt;
            if (j < nzu) { zs = u;      zkt = u + 1 + j; }
            else         { zs = 63 - u; zkt = (63 - u) + 1 + (j - nzu); }
            float* ar = attn + ((size_t)bh * Tn + zs * 32 + lq) * Tn + zkt * 32 + 4 * g;
#pragma unroll
            for (int a = 0; a < 4; ++a)
                *(f32x4*)(ar + 8 * a) = z;
        }
    }

    // combine the two k-chunks' O via LDS; cc==1 writes heads
    if (!cc) {
#pragma unroll
        for (int r = 0; r < 16; ++r) {
            const int tr = (r & 3) + 8 * (r >> 2) + 4 * g;
            olds[slot][tr][lq]      = o0[r];
            olds[slot][tr][32 + lq] = o1[r];
        }
    }
    __syncthreads();
    if (cc) {
        const int b = bh / Hn, hh = bh % Hn;
#pragma unroll
        for (int r = 0; r < 16; ++r) {
            const int tr = (r & 3) + 8 * (r >> 2) + 4 * g;
            const int t = qbase + tr;
            float* base = heads + ((size_t)(b * Tn + t)) * Dn + hh * DHn;
            base[lq]      = o0[r] + olds[slot][tr][lq];
            base[32 + lq] = o1[r] + olds[slot][tr][32 + lq];
        }
    }
}

extern "C" void kernel_launch(void* const* d_in, const int* in_sizes, int n_in,
                              void* d_out, int out_size, void* d_ws, size_t ws_size,
                              hipStream_t stream) {
    (void)in_sizes; (void)n_in; (void)out_size; (void)ws_size;
    const float* x  = (const float*)d_in[0];
    const float* Wq = (const float*)d_in[1];
    const float* bq = (const float*)d_in[2];
    const float* Wk = (const float*)d_in[3];
    const float* bk = (const float*)d_in[4];
    const float* Wv = (const float*)d_in[5];
    const float* bv = (const float*)d_in[6];
    // d_in[7] = attn_mask: structurally causal, handled in-kernel.

    float* heads = (float*)d_out;
    float* attn  = heads + (size_t)Bn * Tn * Dn;

    unsigned short* xbf  = (unsigned short*)d_ws;   // [NX] then [3][NW] weights
    unsigned short* qws  = xbf + NX + 3 * (size_t)NW;
    unsigned short* kws  = qws + NX;
    unsigned short* vtws = kws + NX;
    float* lsum = (float*)(vtws + NX);              // [BH][T]

    hipMemsetAsync(lsum, 0, (size_t)Bn * Hn * Tn * sizeof(float), stream);
    cvt_bf16<<<(NX + 3 * NW) / (256 * 8), 256, 0, stream>>>(x, Wq, Wk, Wv, xbf);
    proj_kernel<<<dim3(64, 12, 3), 256, 0, stream>>>(xbf, xbf + NX, bq, bk, bv,
                                                     qws, kws, vtws);
    attn_pass1<<<768, 256, 0, stream>>>(qws, kws, lsum);
    attn_pass2<<<768, 256, 0, stream>>>(qws, kws, vtws, lsum, heads, attn);
}

// Round 5
// 271.475 us; speedup vs baseline: 2.2349x; 1.1447x over previous
//
#include <hip/hip_runtime.h>

typedef float f32x16 __attribute__((ext_vector_type(16)));
typedef float f32x4  __attribute__((ext_vector_type(4)));
typedef short s16x8  __attribute__((ext_vector_type(8)));
typedef short s16x4  __attribute__((ext_vector_type(4)));

constexpr int Bn = 2, Tn = 2048, Dn = 768, Hn = 12, DHn = 64;
constexpr int NX = Bn * Tn * Dn;   // 3,145,728
constexpr int NW = Dn * Dn;        // 589,824
constexpr float SC2f = 0.125f * 1.44269504088896f;  // (1/sqrt(64))*log2(e)

__device__ __forceinline__ unsigned short f2bf(float f) {
    union { float f; unsigned int i; } c; c.f = f;
    unsigned int u = c.i;
    u += 0x7fffu + ((u >> 16) & 1u);
    return (unsigned short)(u >> 16);
}
__device__ __forceinline__ s16x8 comb(s16x4 lo, s16x4 hi) {
    s16x8 r;
    r[0]=lo[0]; r[1]=lo[1]; r[2]=lo[2]; r[3]=lo[3];
    r[4]=hi[0]; r[5]=hi[1]; r[6]=hi[2]; r[7]=hi[3];
    return r;
}

// ---- f32 -> bf16 one-shot conversion of x, Wq, Wk, Wv into ws ----
__global__ __launch_bounds__(256) void cvt_bf16(
    const float* __restrict__ x,  const float* __restrict__ wq,
    const float* __restrict__ wk, const float* __restrict__ wv,
    unsigned short* __restrict__ out)
{
    const long i8 = ((long)blockIdx.x * 256 + threadIdx.x) * 8;
    const float* src;
    if (i8 < NX)               src = x  + i8;
    else if (i8 < NX + NW)     src = wq + (i8 - NX);
    else if (i8 < NX + 2*NW)   src = wk + (i8 - NX - 2l*NW + NW);
    else                       src = wv + (i8 - NX - 2l*NW);
    f32x4 a = *(const f32x4*)src;
    f32x4 b = *(const f32x4*)(src + 4);
    s16x8 r;
    r[0]=(short)f2bf(a[0]); r[1]=(short)f2bf(a[1]);
    r[2]=(short)f2bf(a[2]); r[3]=(short)f2bf(a[3]);
    r[4]=(short)f2bf(b[0]); r[5]=(short)f2bf(b[1]);
    r[6]=(short)f2bf(b[2]); r[7]=(short)f2bf(b[3]);
    *(s16x8*)(out + i8) = r;
}

// ---- fused QKV projection (bf16 GEMM, z picks Q/K/V) ----
__global__ __launch_bounds__(256) void proj_kernel(
    const unsigned short* __restrict__ xbf,
    const unsigned short* __restrict__ wbf,   // [3][NW]
    const float* __restrict__ bq, const float* __restrict__ bk,
    const float* __restrict__ bv,
    unsigned short* __restrict__ qo, unsigned short* __restrict__ ko,
    unsigned short* __restrict__ vo)
{
    const int z = blockIdx.z;
    const unsigned short* W = wbf + (size_t)z * NW;
    const float* bias = (z == 0) ? bq : (z == 1) ? bk : bv;
    const int tid = threadIdx.x, lane = tid & 63, wid = tid >> 6;
    const int lq = lane & 31, g = lane >> 5;
    const bool vt = (z == 2);
    const int mb = vt ? blockIdx.y : blockIdx.x;
    const int nb = vt ? blockIdx.x : blockIdx.y;
    const int mbase = mb * 64 + (wid & 1) * 32;
    const int nbase = nb * 64 + (wid >> 1) * 32;
    const unsigned short* A  = vt ? W : xbf;
    const unsigned short* Bm = vt ? xbf : W;
    const unsigned short* arow = A  + (size_t)(mbase + lq) * Dn + g * 8;
    const unsigned short* brow = Bm + (size_t)(nbase + lq) * Dn + g * 8;

    f32x16 acc;
#pragma unroll
    for (int i = 0; i < 16; ++i) acc[i] = 0.f;
#pragma unroll 4
    for (int c = 0; c < 48; ++c) {
        s16x8 af = *(const s16x8*)(arow + c * 16);
        s16x8 bf = *(const s16x8*)(brow + c * 16);
        acc = __builtin_amdgcn_mfma_f32_32x32x16_bf16(af, bf, acc, 0, 0, 0);
    }

    if (!vt) {
        unsigned short* out = (z == 0) ? qo : ko;
        const float scale = (z == 0) ? SC2f : 1.f;
        const int e = nbase + lq;
        const float bvl = bias[e];
        const int h = e >> 6, dh = e & 63;
#pragma unroll
        for (int r = 0; r < 16; ++r) {
            const int t = mbase + ((r & 3) + 8 * (r >> 2) + 4 * g);
            const int b = t >> 11, tl = t & (Tn - 1);
            out[((size_t)(b * Hn + h) * Tn + tl) * DHn + dh] = f2bf((acc[r] + bvl) * scale);
        }
    } else {
        const int t = nbase + lq;
        const int b = t >> 11, tl = t & (Tn - 1);
#pragma unroll
        for (int r = 0; r < 16; ++r) {
            const int e = mbase + ((r & 3) + 8 * (r >> 2) + 4 * g);
            const float bvl = bias[e];
            const int h = e >> 6, dh = e & 63;
            vo[((size_t)(b * Hn + h) * DHn + dh) * Tn + tl] = f2bf(acc[r] + bvl);
        }
    }
}

// ---- fully fused causal attention: one block per 32-row strip ----
// 4 waves = 4 k-chunks. Loop1: partial sum-of-exp2 -> LDS reduce (block-local
// softmax denom, no global round-trip). Loop2: normalized P -> attn + PV.
// Fused upper zero-fill. O combined via LDS slots.
__global__ __launch_bounds__(256) void attn_fused(
    const unsigned short* __restrict__ Q,   // [BH][T][Dh], pre-scaled by SC2
    const unsigned short* __restrict__ K,   // [BH][T][Dh]
    const unsigned short* __restrict__ Vt,  // [BH][Dh][T]
    float* __restrict__ heads,              // [B][T][H][Dh]
    float* __restrict__ attn)               // [BH][T][T]
{
    __shared__ float pls[4][32];
    __shared__ float olds[3][32][64];

    const int tid = threadIdx.x, lane = tid & 63, wid = tid >> 6;
    const int lq = lane & 31, g = lane >> 5;
    // XCD-chunked: XCD k owns heads [3k,3k+3); within a head, longest strip first.
    const int n2 = ((int)blockIdx.x & 7) * 192 + ((int)blockIdx.x >> 3);
    const int bh = n2 >> 6;
    const int s  = 63 - (n2 & 63);
    const int qbase = s * 32;
    const int n  = s + 1;                    // causal tiles 0..s (s masked)
    const int lo = wid * n / 4, hi = (wid + 1) * n / 4;

    const unsigned short* Qb = Q  + ((size_t)bh * Tn + qbase) * DHn;
    const unsigned short* Kb = K  + (size_t)bh * Tn * DHn;
    const unsigned short* Vb = Vt + (size_t)bh * DHn * Tn;

    s16x8 qf[4];
#pragma unroll
    for (int c = 0; c < 4; ++c)
        qf[c] = *(const s16x8*)(Qb + lq * DHn + c * 16 + g * 8);

    // ---- loop1: partial row sums of exp2(q.k) over this wave's chunk ----
    float ls = 0.f;
    for (int kt = lo; kt < hi; ++kt) {
        const unsigned short* krow = Kb + (size_t)(kt * 32 + lq) * DHn + g * 8;
        f32x16 acc;
#pragma unroll
        for (int i = 0; i < 16; ++i) acc[i] = 0.f;
#pragma unroll
        for (int c = 0; c < 4; ++c)
            acc = __builtin_amdgcn_mfma_f32_32x32x16_bf16(
                *(const s16x8*)(krow + c * 16), qf[c], acc, 0, 0, 0);
        if (kt == s) {
#pragma unroll
            for (int r = 0; r < 16; ++r) {
                const int koff = (r & 3) + 8 * (r >> 2) + 4 * g;
                ls += (koff <= lq) ? exp2f(acc[r]) : 0.f;
            }
        } else {
#pragma unroll
            for (int r = 0; r < 16; ++r) ls += exp2f(acc[r]);
        }
    }
    ls += __shfl_xor(ls, 32);                // combine g-halves
    if (g == 0) pls[wid][lq] = ls;
    __syncthreads();
    const float rl = 1.f / (pls[0][lq] + pls[1][lq] + pls[2][lq] + pls[3][lq]);

    // ---- loop2: P -> attn, O += P.V ----
    f32x16 o0, o1;
#pragma unroll
    for (int i = 0; i < 16; ++i) { o0[i] = 0.f; o1[i] = 0.f; }
    const size_t arow0 = ((size_t)bh * Tn + (qbase + lq)) * Tn;

    for (int kt = lo; kt < hi; ++kt) {
        const unsigned short* krow = Kb + (size_t)(kt * 32 + lq) * DHn + g * 8;
        f32x16 acc;
#pragma unroll
        for (int i = 0; i < 16; ++i) acc[i] = 0.f;
#pragma unroll
        for (int c = 0; c < 4; ++c)
            acc = __builtin_amdgcn_mfma_f32_32x32x16_bf16(
                *(const s16x8*)(krow + c * 16), qf[c], acc, 0, 0, 0);

        const bool diag = (kt == s);
        float pv[16];
#pragma unroll
        for (int r = 0; r < 16; ++r) {
            const int koff = (r & 3) + 8 * (r >> 2) + 4 * g;
            float e = exp2f(acc[r]) * rl;
            pv[r] = (diag && koff > lq) ? 0.f : e;
        }

        float* ar = attn + arow0 + kt * 32 + 4 * g;
#pragma unroll
        for (int a = 0; a < 4; ++a) {
            f32x4 w;
            w[0]=pv[4*a+0]; w[1]=pv[4*a+1]; w[2]=pv[4*a+2]; w[3]=pv[4*a+3];
            *(f32x4*)(ar + 8 * a) = w;
        }

        s16x8 pa0, pa1;
#pragma unroll
        for (int j = 0; j < 8; ++j) {
            pa0[j] = (short)f2bf(pv[j]);
            pa1[j] = (short)f2bf(pv[8 + j]);
        }
        const unsigned short* vr0 = Vb + (size_t)lq * Tn + kt * 32;
        const unsigned short* vr1 = Vb + (size_t)(32 + lq) * Tn + kt * 32;
#pragma unroll
        for (int c2 = 0; c2 < 2; ++c2) {
            const s16x8 pa = c2 ? pa1 : pa0;
            s16x4 lo0 = *(const s16x4*)(vr0 + c2 * 16 + 4 * g);
            s16x4 hi0 = *(const s16x4*)(vr0 + c2 * 16 + 8 + 4 * g);
            o0 = __builtin_amdgcn_mfma_f32_32x32x16_bf16(pa, comb(lo0, hi0), o0, 0, 0, 0);
            s16x4 lo1 = *(const s16x4*)(vr1 + c2 * 16 + 4 * g);
            s16x4 hi1 = *(const s16x4*)(vr1 + c2 * 16 + 8 + 4 * g);
            o1 = __builtin_amdgcn_mfma_f32_32x32x16_bf16(pa, comb(lo1, hi1), o1, 0, 0, 0);
        }
    }

    // ---- fused zero-fill of this strip's strictly-upper tiles ----
    {
        f32x4 z; z[0]=0.f; z[1]=0.f; z[2]=0.f; z[3]=0.f;
        for (int kt = s + 1 + wid; kt < 64; kt += 4) {
            float* ar = attn + arow0 + kt * 32 + 4 * g;
#pragma unroll
            for (int a = 0; a < 4; ++a)
                *(f32x4*)(ar + 8 * a) = z;
        }
    }

    // ---- combine 4 chunks' O; wave 0 writes heads ----
    if (wid) {
#pragma unroll
        for (int r = 0; r < 16; ++r) {
            const int tr = (r & 3) + 8 * (r >> 2) + 4 * g;
            olds[wid - 1][tr][lq]      = o0[r];
            olds[wid - 1][tr][32 + lq] = o1[r];
        }
    }
    __syncthreads();
    if (!wid) {
        const int b = bh / Hn, hh = bh % Hn;
#pragma unroll
        for (int r = 0; r < 16; ++r) {
            const int tr = (r & 3) + 8 * (r >> 2) + 4 * g;
            const int t = qbase + tr;
            float* base = heads + ((size_t)(b * Tn + t)) * Dn + hh * DHn;
            base[lq]      = o0[r] + olds[0][tr][lq] + olds[1][tr][lq] + olds[2][tr][lq];
            base[32 + lq] = o1[r] + olds[0][tr][32 + lq] + olds[1][tr][32 + lq] + olds[2][tr][32 + lq];
        }
    }
}

extern "C" void kernel_launch(void* const* d_in, const int* in_sizes, int n_in,
                              void* d_out, int out_size, void* d_ws, size_t ws_size,
                              hipStream_t stream) {
    (void)in_sizes; (void)n_in; (void)out_size; (void)ws_size;
    const float* x  = (const float*)d_in[0];
    const float* Wq = (const float*)d_in[1];
    const float* bq = (const float*)d_in[2];
    const float* Wk = (const float*)d_in[3];
    const float* bk = (const float*)d_in[4];
    const float* Wv = (const float*)d_in[5];
    const float* bv = (const float*)d_in[6];
    // d_in[7] = attn_mask: structurally causal, handled in-kernel.

    float* heads = (float*)d_out;
    float* attn  = heads + (size_t)Bn * Tn * Dn;

    unsigned short* xbf  = (unsigned short*)d_ws;   // [NX] then [3][NW] weights
    unsigned short* qws  = xbf + NX + 3 * (size_t)NW;
    unsigned short* kws  = qws + NX;
    unsigned short* vtws = kws + NX;

    cvt_bf16<<<(NX + 3 * NW) / (256 * 8), 256, 0, stream>>>(x, Wq, Wk, Wv, xbf);
    proj_kernel<<<dim3(64, 12, 3), 256, 0, stream>>>(xbf, xbf + NX, bq, bk, bv,
                                                     qws, kws, vtws);
    attn_fused<<<1536, 256, 0, stream>>>(qws, kws, vtws, heads, attn);
}

// Round 6
// 259.381 us; speedup vs baseline: 2.3391x; 1.0466x over previous
//
#include <hip/hip_runtime.h>

typedef float f32x16 __attribute__((ext_vector_type(16)));
typedef float f32x4  __attribute__((ext_vector_type(4)));
typedef short s16x8  __attribute__((ext_vector_type(8)));
typedef short s16x4  __attribute__((ext_vector_type(4)));

constexpr int Bn = 2, Tn = 2048, Dn = 768, Hn = 12, DHn = 64;
constexpr int NX = Bn * Tn * Dn;   // 3,145,728
constexpr int NW = Dn * Dn;        // 589,824
constexpr float SC2f = 0.125f * 1.44269504088896f;  // (1/sqrt(64))*log2(e)

__device__ __forceinline__ unsigned short f2bf(float f) {
    union { float f; unsigned int i; } c; c.f = f;
    unsigned int u = c.i;
    u += 0x7fffu + ((u >> 16) & 1u);
    return (unsigned short)(u >> 16);
}
__device__ __forceinline__ unsigned int cvtpk(float lo, float hi) {
    unsigned int r;
    asm("v_cvt_pk_bf16_f32 %0, %1, %2" : "=v"(r) : "v"(lo), "v"(hi));
    return r;
}
__device__ __forceinline__ s16x8 comb(s16x4 lo, s16x4 hi) {
    s16x8 r;
    r[0]=lo[0]; r[1]=lo[1]; r[2]=lo[2]; r[3]=lo[3];
    r[4]=hi[0]; r[5]=hi[1]; r[6]=hi[2]; r[7]=hi[3];
    return r;
}

// ---- f32 -> bf16 one-shot conversion of x, Wq, Wk, Wv into ws ----
__global__ __launch_bounds__(256) void cvt_bf16(
    const float* __restrict__ x,  const float* __restrict__ wq,
    const float* __restrict__ wk, const float* __restrict__ wv,
    unsigned short* __restrict__ out)
{
    const long i8 = ((long)blockIdx.x * 256 + threadIdx.x) * 8;
    const float* src;
    if (i8 < NX)               src = x  + i8;
    else if (i8 < NX + NW)     src = wq + (i8 - NX);
    else if (i8 < NX + 2*NW)   src = wk + (i8 - NX - 2l*NW + NW);
    else                       src = wv + (i8 - NX - 2l*NW);
    f32x4 a = *(const f32x4*)src;
    f32x4 b = *(const f32x4*)(src + 4);
    union { unsigned int u[4]; s16x8 v; } P;
    P.u[0] = cvtpk(a[0], a[1]); P.u[1] = cvtpk(a[2], a[3]);
    P.u[2] = cvtpk(b[0], b[1]); P.u[3] = cvtpk(b[2], b[3]);
    *(s16x8*)(out + i8) = P.v;
}

// ---- fused QKV projection (bf16 GEMM, z picks Q/K/V) ----
__global__ __launch_bounds__(256) void proj_kernel(
    const unsigned short* __restrict__ xbf,
    const unsigned short* __restrict__ wbf,   // [3][NW]
    const float* __restrict__ bq, const float* __restrict__ bk,
    const float* __restrict__ bv,
    unsigned short* __restrict__ qo, unsigned short* __restrict__ ko,
    unsigned short* __restrict__ vo)
{
    const int z = blockIdx.z;
    const unsigned short* W = wbf + (size_t)z * NW;
    const float* bias = (z == 0) ? bq : (z == 1) ? bk : bv;
    const int tid = threadIdx.x, lane = tid & 63, wid = tid >> 6;
    const int lq = lane & 31, g = lane >> 5;
    const bool vt = (z == 2);
    const int mb = vt ? blockIdx.y : blockIdx.x;
    const int nb = vt ? blockIdx.x : blockIdx.y;
    const int mbase = mb * 64 + (wid & 1) * 32;
    const int nbase = nb * 64 + (wid >> 1) * 32;
    const unsigned short* A  = vt ? W : xbf;
    const unsigned short* Bm = vt ? xbf : W;
    const unsigned short* arow = A  + (size_t)(mbase + lq) * Dn + g * 8;
    const unsigned short* brow = Bm + (size_t)(nbase + lq) * Dn + g * 8;

    f32x16 acc;
#pragma unroll
    for (int i = 0; i < 16; ++i) acc[i] = 0.f;
#pragma unroll 4
    for (int c = 0; c < 48; ++c) {
        s16x8 af = *(const s16x8*)(arow + c * 16);
        s16x8 bf = *(const s16x8*)(brow + c * 16);
        acc = __builtin_amdgcn_mfma_f32_32x32x16_bf16(af, bf, acc, 0, 0, 0);
    }

    if (!vt) {
        unsigned short* out = (z == 0) ? qo : ko;
        const float scale = (z == 0) ? SC2f : 1.f;
        const int e = nbase + lq;
        const float bvl = bias[e];
        const int h = e >> 6, dh = e & 63;
#pragma unroll
        for (int r = 0; r < 16; ++r) {
            const int t = mbase + ((r & 3) + 8 * (r >> 2) + 4 * g);
            const int b = t >> 11, tl = t & (Tn - 1);
            out[((size_t)(b * Hn + h) * Tn + tl) * DHn + dh] = f2bf((acc[r] + bvl) * scale);
        }
    } else {
        const int t = nbase + lq;
        const int b = t >> 11, tl = t & (Tn - 1);
#pragma unroll
        for (int r = 0; r < 16; ++r) {
            const int e = mbase + ((r & 3) + 8 * (r >> 2) + 4 * g);
            const float bvl = bias[e];
            const int h = e >> 6, dh = e & 63;
            vo[((size_t)(b * Hn + h) * DHn + dh) * Tn + tl] = f2bf(acc[r] + bvl);
        }
    }
}

// ---- fully fused causal attention: one block per 32-row strip ----
// 4 waves = 4 k-chunks. Loop1: partial sum-of-exp2 -> LDS reduce. Loop2:
// normalized P -> per-wave LDS transpose -> full-line coalesced attn stores,
// PV from registers. Coalesced upper zero-fill. O combined via LDS (overlaid
// with the transpose buffers, separated by a barrier).
__global__ __launch_bounds__(256) void attn_fused(
    const unsigned short* __restrict__ Q,   // [BH][T][Dh], pre-scaled by SC2
    const unsigned short* __restrict__ K,   // [BH][T][Dh]
    const unsigned short* __restrict__ Vt,  // [BH][Dh][T]
    float* __restrict__ heads,              // [B][T][H][Dh]
    float* __restrict__ attn)               // [BH][T][T]
{
    __shared__ float pls[4][32];
    __shared__ float smem[6144];            // 24KB: PT[wid*1024] in loops; olds at end

    const int tid = threadIdx.x, lane = tid & 63, wid = tid >> 6;
    const int lq = lane & 31, g = lane >> 5;
    // XCD-chunked: XCD k owns heads [3k,3k+3); within a head, longest strip first.
    const int n2 = ((int)blockIdx.x & 7) * 192 + ((int)blockIdx.x >> 3);
    const int bh = n2 >> 6;
    const int s  = 63 - (n2 & 63);
    const int qbase = s * 32;
    const int n  = s + 1;
    const int lo = wid * n / 4, hi = (wid + 1) * n / 4;

    const unsigned short* Qb = Q  + ((size_t)bh * Tn + qbase) * DHn;
    const unsigned short* Kb = K  + (size_t)bh * Tn * DHn;
    const unsigned short* Vb = Vt + (size_t)bh * DHn * Tn;
    const size_t abase = ((size_t)bh * Tn + qbase) * Tn;

    s16x8 qf[4];
#pragma unroll
    for (int c = 0; c < 4; ++c)
        qf[c] = *(const s16x8*)(Qb + lq * DHn + c * 16 + g * 8);

    // ---- loop1: partial row sums of exp2(q.k) ----
    float ls = 0.f;
    for (int kt = lo; kt < hi; ++kt) {
        const unsigned short* krow = Kb + (size_t)(kt * 32 + lq) * DHn + g * 8;
        f32x16 acc;
#pragma unroll
        for (int i = 0; i < 16; ++i) acc[i] = 0.f;
#pragma unroll
        for (int c = 0; c < 4; ++c)
            acc = __builtin_amdgcn_mfma_f32_32x32x16_bf16(
                *(const s16x8*)(krow + c * 16), qf[c], acc, 0, 0, 0);
        if (kt == s) {
#pragma unroll
            for (int r = 0; r < 16; ++r) {
                const int koff = (r & 3) + 8 * (r >> 2) + 4 * g;
                ls += (koff <= lq) ? exp2f(acc[r]) : 0.f;
            }
        } else {
#pragma unroll
            for (int r = 0; r < 16; ++r) ls += exp2f(acc[r]);
        }
    }
    ls += __shfl_xor(ls, 32);
    if (g == 0) pls[wid][lq] = ls;
    __syncthreads();
    const float rl = 1.f / (pls[0][lq] + pls[1][lq] + pls[2][lq] + pls[3][lq]);

    // ---- loop2: P -> (LDS transpose) -> attn, O += P.V ----
    f32x16 o0, o1;
#pragma unroll
    for (int i = 0; i < 16; ++i) { o0[i] = 0.f; o1[i] = 0.f; }

    float* PT = smem + wid * 1024;          // per-wave 32x32 f32 tile
    const int rq = lane >> 3;               // 0..7 (transpose-read row group)
    const int rk = (lane & 7) * 4;          // 0..28 (col group)
    const int rcol = rk ^ (rq << 2);        // swizzled LDS col

    for (int kt = lo; kt < hi; ++kt) {
        const unsigned short* krow = Kb + (size_t)(kt * 32 + lq) * DHn + g * 8;
        f32x16 acc;
#pragma unroll
        for (int i = 0; i < 16; ++i) acc[i] = 0.f;
#pragma unroll
        for (int c = 0; c < 4; ++c)
            acc = __builtin_amdgcn_mfma_f32_32x32x16_bf16(
                *(const s16x8*)(krow + c * 16), qf[c], acc, 0, 0, 0);

        const bool diag = (kt == s);
        float pv[16];
#pragma unroll
        for (int r = 0; r < 16; ++r) {
            const int koff = (r & 3) + 8 * (r >> 2) + 4 * g;
            float e = exp2f(acc[r]) * rl;
            pv[r] = (diag && koff > lq) ? 0.f : e;
        }

        // P-tile into per-wave LDS (XOR-swizzled, bank-uniform b128)
#pragma unroll
        for (int a = 0; a < 4; ++a) {
            const int c0 = (4 * g + 8 * a) ^ ((lq & 7) << 2);
            f32x4 w;
            w[0]=pv[4*a+0]; w[1]=pv[4*a+1]; w[2]=pv[4*a+2]; w[3]=pv[4*a+3];
            *(f32x4*)&PT[lq * 32 + c0] = w;
        }
        asm volatile("s_waitcnt lgkmcnt(0)" ::: "memory");
        // transpose-read + full-line coalesced stores (8 lines / instr)
#pragma unroll
        for (int jj = 0; jj < 4; ++jj) {
            const int q = 8 * jj + rq;
            f32x4 w = *(const f32x4*)&PT[q * 32 + rcol];
            *(f32x4*)(attn + abase + (size_t)q * Tn + kt * 32 + rk) = w;
        }

        // PV: P (bf16) as A-operand via cvt_pk; V^T with matching k-bijection
        union { unsigned int u[4]; s16x8 v; } P0, P1;
        P0.u[0]=cvtpk(pv[0],pv[1]);   P0.u[1]=cvtpk(pv[2],pv[3]);
        P0.u[2]=cvtpk(pv[4],pv[5]);   P0.u[3]=cvtpk(pv[6],pv[7]);
        P1.u[0]=cvtpk(pv[8],pv[9]);   P1.u[1]=cvtpk(pv[10],pv[11]);
        P1.u[2]=cvtpk(pv[12],pv[13]); P1.u[3]=cvtpk(pv[14],pv[15]);

        const unsigned short* vr0 = Vb + (size_t)lq * Tn + kt * 32;
        const unsigned short* vr1 = Vb + (size_t)(32 + lq) * Tn + kt * 32;
#pragma unroll
        for (int c2 = 0; c2 < 2; ++c2) {
            const s16x8 pa = c2 ? P1.v : P0.v;
            s16x4 lo0 = *(const s16x4*)(vr0 + c2 * 16 + 4 * g);
            s16x4 hi0 = *(const s16x4*)(vr0 + c2 * 16 + 8 + 4 * g);
            o0 = __builtin_amdgcn_mfma_f32_32x32x16_bf16(pa, comb(lo0, hi0), o0, 0, 0, 0);
            s16x4 lo1 = *(const s16x4*)(vr1 + c2 * 16 + 4 * g);
            s16x4 hi1 = *(const s16x4*)(vr1 + c2 * 16 + 8 + 4 * g);
            o1 = __builtin_amdgcn_mfma_f32_32x32x16_bf16(pa, comb(lo1, hi1), o1, 0, 0, 0);
        }
    }

    // ---- coalesced zero-fill of this strip's strictly-upper region ----
    {
        const int zc0 = (s + 1) * 32;       // first zero column (f32 units)
        f32x4 z; z[0]=0.f; z[1]=0.f; z[2]=0.f; z[3]=0.f;
        for (int row = wid; row < 32; row += 4) {
            float* rp = attn + abase + (size_t)row * Tn;
            for (int c = zc0 + lane * 4; c < Tn; c += 256)
                *(f32x4*)(rp + c) = z;
        }
    }

    // ---- combine 4 chunks' O (olds overlays PT; barrier separates) ----
    __syncthreads();
    if (wid) {
#pragma unroll
        for (int r = 0; r < 16; ++r) {
            const int tr = (r & 3) + 8 * (r >> 2) + 4 * g;
            smem[(((wid - 1) * 32) + tr) * 64 + lq]      = o0[r];
            smem[(((wid - 1) * 32) + tr) * 64 + 32 + lq] = o1[r];
        }
    }
    __syncthreads();
    if (!wid) {
        const int b = bh / Hn, hh = bh % Hn;
#pragma unroll
        for (int r = 0; r < 16; ++r) {
            const int tr = (r & 3) + 8 * (r >> 2) + 4 * g;
            const int t = qbase + tr;
            float* base = heads + ((size_t)(b * Tn + t)) * Dn + hh * DHn;
            base[lq]      = o0[r] + smem[tr * 64 + lq]
                          + smem[(32 + tr) * 64 + lq] + smem[(64 + tr) * 64 + lq];
            base[32 + lq] = o1[r] + smem[tr * 64 + 32 + lq]
                          + smem[(32 + tr) * 64 + 32 + lq] + smem[(64 + tr) * 64 + 32 + lq];
        }
    }
}

extern "C" void kernel_launch(void* const* d_in, const int* in_sizes, int n_in,
                              void* d_out, int out_size, void* d_ws, size_t ws_size,
                              hipStream_t stream) {
    (void)in_sizes; (void)n_in; (void)out_size; (void)ws_size;
    const float* x  = (const float*)d_in[0];
    const float* Wq = (const float*)d_in[1];
    const float* bq = (const float*)d_in[2];
    const float* Wk = (const float*)d_in[3];
    const float* bk = (const float*)d_in[4];
    const float* Wv = (const float*)d_in[5];
    const float* bv = (const float*)d_in[6];
    // d_in[7] = attn_mask: structurally causal, handled in-kernel.

    float* heads = (float*)d_out;
    float* attn  = heads + (size_t)Bn * Tn * Dn;

    unsigned short* xbf  = (unsigned short*)d_ws;   // [NX] then [3][NW] weights
    unsigned short* qws  = xbf + NX + 3 * (size_t)NW;
    unsigned short* kws  = qws + NX;
    unsigned short* vtws = kws + NX;

    cvt_bf16<<<(NX + 3 * NW) / (256 * 8), 256, 0, stream>>>(x, Wq, Wk, Wv, xbf);
    proj_kernel<<<dim3(64, 12, 3), 256, 0, stream>>>(xbf, xbf + NX, bq, bk, bv,
                                                     qws, kws, vtws);
    attn_fused<<<1536, 256, 0, stream>>>(qws, kws, vtws, heads, attn);
}

// Round 7
// 253.663 us; speedup vs baseline: 2.3918x; 1.0225x over previous
//
#include <hip/hip_runtime.h>

typedef float f32x16 __attribute__((ext_vector_type(16)));
typedef float f32x4  __attribute__((ext_vector_type(4)));
typedef short s16x8  __attribute__((ext_vector_type(8)));
typedef short s16x4  __attribute__((ext_vector_type(4)));

constexpr int Bn = 2, Tn = 2048, Dn = 768, Hn = 12, DHn = 64;
constexpr int NX = Bn * Tn * Dn;   // 3,145,728
constexpr int NW = Dn * Dn;        // 589,824
constexpr float SC2f = 0.125f * 1.44269504088896f;  // (1/sqrt(64))*log2(e)

__device__ __forceinline__ unsigned short f2bf(float f) {
    union { float f; unsigned int i; } c; c.f = f;
    unsigned int u = c.i;
    u += 0x7fffu + ((u >> 16) & 1u);
    return (unsigned short)(u >> 16);
}
__device__ __forceinline__ unsigned int cvtpk(float lo, float hi) {
    unsigned int r;
    asm("v_cvt_pk_bf16_f32 %0, %1, %2" : "=v"(r) : "v"(lo), "v"(hi));
    return r;
}
__device__ __forceinline__ s16x8 comb(s16x4 lo, s16x4 hi) {
    s16x8 r;
    r[0]=lo[0]; r[1]=lo[1]; r[2]=lo[2]; r[3]=lo[3];
    r[4]=hi[0]; r[5]=hi[1]; r[6]=hi[2]; r[7]=hi[3];
    return r;
}

// ---- f32 -> bf16 one-shot conversion of x, Wq, Wk, Wv into ws ----
__global__ __launch_bounds__(256) void cvt_bf16(
    const float* __restrict__ x,  const float* __restrict__ wq,
    const float* __restrict__ wk, const float* __restrict__ wv,
    unsigned short* __restrict__ out)
{
    const long i8 = ((long)blockIdx.x * 256 + threadIdx.x) * 8;
    const float* src;
    if (i8 < NX)               src = x  + i8;
    else if (i8 < NX + NW)     src = wq + (i8 - NX);
    else if (i8 < NX + 2*NW)   src = wk + (i8 - NX - 2l*NW + NW);
    else                       src = wv + (i8 - NX - 2l*NW);
    f32x4 a = *(const f32x4*)src;
    f32x4 b = *(const f32x4*)(src + 4);
    union { unsigned int u[4]; s16x8 v; } P;
    P.u[0] = cvtpk(a[0], a[1]); P.u[1] = cvtpk(a[2], a[3]);
    P.u[2] = cvtpk(b[0], b[1]); P.u[3] = cvtpk(b[2], b[3]);
    *(s16x8*)(out + i8) = P.v;
}

// ---- fused QKV projection (bf16 GEMM, z picks Q/K/V) ----
__global__ __launch_bounds__(256) void proj_kernel(
    const unsigned short* __restrict__ xbf,
    const unsigned short* __restrict__ wbf,   // [3][NW]
    const float* __restrict__ bq, const float* __restrict__ bk,
    const float* __restrict__ bv,
    unsigned short* __restrict__ qo, unsigned short* __restrict__ ko,
    unsigned short* __restrict__ vo)
{
    const int z = blockIdx.z;
    const unsigned short* W = wbf + (size_t)z * NW;
    const float* bias = (z == 0) ? bq : (z == 1) ? bk : bv;
    const int tid = threadIdx.x, lane = tid & 63, wid = tid >> 6;
    const int lq = lane & 31, g = lane >> 5;
    const bool vt = (z == 2);
    const int mb = vt ? blockIdx.y : blockIdx.x;
    const int nb = vt ? blockIdx.x : blockIdx.y;
    const int mbase = mb * 64 + (wid & 1) * 32;
    const int nbase = nb * 64 + (wid >> 1) * 32;
    const unsigned short* A  = vt ? W : xbf;
    const unsigned short* Bm = vt ? xbf : W;
    const unsigned short* arow = A  + (size_t)(mbase + lq) * Dn + g * 8;
    const unsigned short* brow = Bm + (size_t)(nbase + lq) * Dn + g * 8;

    f32x16 acc;
#pragma unroll
    for (int i = 0; i < 16; ++i) acc[i] = 0.f;
#pragma unroll 4
    for (int c = 0; c < 48; ++c) {
        s16x8 af = *(const s16x8*)(arow + c * 16);
        s16x8 bf = *(const s16x8*)(brow + c * 16);
        acc = __builtin_amdgcn_mfma_f32_32x32x16_bf16(af, bf, acc, 0, 0, 0);
    }

    if (!vt) {
        unsigned short* out = (z == 0) ? qo : ko;
        const float scale = (z == 0) ? SC2f : 1.f;
        const int e = nbase + lq;
        const float bvl = bias[e];
        const int h = e >> 6, dh = e & 63;
#pragma unroll
        for (int r = 0; r < 16; ++r) {
            const int t = mbase + ((r & 3) + 8 * (r >> 2) + 4 * g);
            const int b = t >> 11, tl = t & (Tn - 1);
            out[((size_t)(b * Hn + h) * Tn + tl) * DHn + dh] = f2bf((acc[r] + bvl) * scale);
        }
    } else {
        const int t = nbase + lq;
        const int b = t >> 11, tl = t & (Tn - 1);
#pragma unroll
        for (int r = 0; r < 16; ++r) {
            const int e = mbase + ((r & 3) + 8 * (r >> 2) + 4 * g);
            const float bvl = bias[e];
            const int h = e >> 6, dh = e & 63;
            vo[((size_t)(b * Hn + h) * DHn + dh) * Tn + tl] = f2bf(acc[r] + bvl);
        }
    }
}

// ---- fully fused causal attention: one block per 32-row strip ----
// 4 waves = 4 k-chunks. Loop1: partial sum-of-exp2 -> LDS reduce. Loop2:
// normalized P -> per-wave LDS transpose -> full-line NON-TEMPORAL attn
// stores (no L2 allocate: keeps K/V resident; full lines: no RMW), PV from
// registers. Coalesced NT upper zero-fill. O combined via overlaid LDS.
__global__ __launch_bounds__(256) void attn_fused(
    const unsigned short* __restrict__ Q,   // [BH][T][Dh], pre-scaled by SC2
    const unsigned short* __restrict__ K,   // [BH][T][Dh]
    const unsigned short* __restrict__ Vt,  // [BH][Dh][T]
    float* __restrict__ heads,              // [B][T][H][Dh]
    float* __restrict__ attn)               // [BH][T][T]
{
    __shared__ float pls[4][32];
    __shared__ float smem[6144];            // 24KB: PT[wid*1024] in loops; olds at end

    const int tid = threadIdx.x, lane = tid & 63, wid = tid >> 6;
    const int lq = lane & 31, g = lane >> 5;
    // XCD-chunked: XCD k owns heads [3k,3k+3); within a head, longest strip first.
    const int n2 = ((int)blockIdx.x & 7) * 192 + ((int)blockIdx.x >> 3);
    const int bh = n2 >> 6;
    const int s  = 63 - (n2 & 63);
    const int qbase = s * 32;
    const int n  = s + 1;
    const int lo = wid * n / 4, hi = (wid + 1) * n / 4;

    const unsigned short* Qb = Q  + ((size_t)bh * Tn + qbase) * DHn;
    const unsigned short* Kb = K  + (size_t)bh * Tn * DHn;
    const unsigned short* Vb = Vt + (size_t)bh * DHn * Tn;
    const size_t abase = ((size_t)bh * Tn + qbase) * Tn;

    s16x8 qf[4];
#pragma unroll
    for (int c = 0; c < 4; ++c)
        qf[c] = *(const s16x8*)(Qb + lq * DHn + c * 16 + g * 8);

    // ---- loop1: partial row sums of exp2(q.k) ----
    float ls = 0.f;
    for (int kt = lo; kt < hi; ++kt) {
        const unsigned short* krow = Kb + (size_t)(kt * 32 + lq) * DHn + g * 8;
        f32x16 acc;
#pragma unroll
        for (int i = 0; i < 16; ++i) acc[i] = 0.f;
#pragma unroll
        for (int c = 0; c < 4; ++c)
            acc = __builtin_amdgcn_mfma_f32_32x32x16_bf16(
                *(const s16x8*)(krow + c * 16), qf[c], acc, 0, 0, 0);
        if (kt == s) {
#pragma unroll
            for (int r = 0; r < 16; ++r) {
                const int koff = (r & 3) + 8 * (r >> 2) + 4 * g;
                ls += (koff <= lq) ? exp2f(acc[r]) : 0.f;
            }
        } else {
#pragma unroll
            for (int r = 0; r < 16; ++r) ls += exp2f(acc[r]);
        }
    }
    ls += __shfl_xor(ls, 32);
    if (g == 0) pls[wid][lq] = ls;
    __syncthreads();
    const float rl = 1.f / (pls[0][lq] + pls[1][lq] + pls[2][lq] + pls[3][lq]);

    // ---- loop2: P -> (LDS transpose) -> attn, O += P.V ----
    f32x16 o0, o1;
#pragma unroll
    for (int i = 0; i < 16; ++i) { o0[i] = 0.f; o1[i] = 0.f; }

    float* PT = smem + wid * 1024;          // per-wave 32x32 f32 tile
    const int rq = lane >> 3;               // 0..7 (transpose-read row group)
    const int rk = (lane & 7) * 4;          // 0..28 (col group)
    const int rcol = rk ^ (rq << 2);        // swizzled LDS col

    for (int kt = lo; kt < hi; ++kt) {
        const unsigned short* krow = Kb + (size_t)(kt * 32 + lq) * DHn + g * 8;
        f32x16 acc;
#pragma unroll
        for (int i = 0; i < 16; ++i) acc[i] = 0.f;
#pragma unroll
        for (int c = 0; c < 4; ++c)
            acc = __builtin_amdgcn_mfma_f32_32x32x16_bf16(
                *(const s16x8*)(krow + c * 16), qf[c], acc, 0, 0, 0);

        const bool diag = (kt == s);
        float pv[16];
#pragma unroll
        for (int r = 0; r < 16; ++r) {
            const int koff = (r & 3) + 8 * (r >> 2) + 4 * g;
            float e = exp2f(acc[r]) * rl;
            pv[r] = (diag && koff > lq) ? 0.f : e;
        }

        // P-tile into per-wave LDS (XOR-swizzled, bank-uniform b128)
#pragma unroll
        for (int a = 0; a < 4; ++a) {
            const int c0 = (4 * g + 8 * a) ^ ((lq & 7) << 2);
            f32x4 w;
            w[0]=pv[4*a+0]; w[1]=pv[4*a+1]; w[2]=pv[4*a+2]; w[3]=pv[4*a+3];
            *(f32x4*)&PT[lq * 32 + c0] = w;
        }
        asm volatile("s_waitcnt lgkmcnt(0)" ::: "memory");
        // transpose-read + full-line NT stores (8 full 128B lines / instr)
#pragma unroll
        for (int jj = 0; jj < 4; ++jj) {
            const int q = 8 * jj + rq;
            f32x4 w = *(const f32x4*)&PT[q * 32 + rcol];
            __builtin_nontemporal_store(w,
                (f32x4*)(attn + abase + (size_t)q * Tn + kt * 32 + rk));
        }

        // PV: P (bf16) as A-operand via cvt_pk; V^T with matching k-bijection
        union { unsigned int u[4]; s16x8 v; } P0, P1;
        P0.u[0]=cvtpk(pv[0],pv[1]);   P0.u[1]=cvtpk(pv[2],pv[3]);
        P0.u[2]=cvtpk(pv[4],pv[5]);   P0.u[3]=cvtpk(pv[6],pv[7]);
        P1.u[0]=cvtpk(pv[8],pv[9]);   P1.u[1]=cvtpk(pv[10],pv[11]);
        P1.u[2]=cvtpk(pv[12],pv[13]); P1.u[3]=cvtpk(pv[14],pv[15]);

        const unsigned short* vr0 = Vb + (size_t)lq * Tn + kt * 32;
        const unsigned short* vr1 = Vb + (size_t)(32 + lq) * Tn + kt * 32;
#pragma unroll
        for (int c2 = 0; c2 < 2; ++c2) {
            const s16x8 pa = c2 ? P1.v : P0.v;
            s16x4 lo0 = *(const s16x4*)(vr0 + c2 * 16 + 4 * g);
            s16x4 hi0 = *(const s16x4*)(vr0 + c2 * 16 + 8 + 4 * g);
            o0 = __builtin_amdgcn_mfma_f32_32x32x16_bf16(pa, comb(lo0, hi0), o0, 0, 0, 0);
            s16x4 lo1 = *(const s16x4*)(vr1 + c2 * 16 + 4 * g);
            s16x4 hi1 = *(const s16x4*)(vr1 + c2 * 16 + 8 + 4 * g);
            o1 = __builtin_amdgcn_mfma_f32_32x32x16_bf16(pa, comb(lo1, hi1), o1, 0, 0, 0);
        }
    }

    // ---- coalesced NT zero-fill of this strip's strictly-upper region ----
    {
        const int zc0 = (s + 1) * 32;       // first zero column (f32 units)
        f32x4 z; z[0]=0.f; z[1]=0.f; z[2]=0.f; z[3]=0.f;
        for (int row = wid; row < 32; row += 4) {
            float* rp = attn + abase + (size_t)row * Tn;
            for (int c = zc0 + lane * 4; c < Tn; c += 256)
                __builtin_nontemporal_store(z, (f32x4*)(rp + c));
        }
    }

    // ---- combine 4 chunks' O (olds overlays PT; barrier separates) ----
    __syncthreads();
    if (wid) {
#pragma unroll
        for (int r = 0; r < 16; ++r) {
            const int tr = (r & 3) + 8 * (r >> 2) + 4 * g;
            smem[(((wid - 1) * 32) + tr) * 64 + lq]      = o0[r];
            smem[(((wid - 1) * 32) + tr) * 64 + 32 + lq] = o1[r];
        }
    }
    __syncthreads();
    if (!wid) {
        const int b = bh / Hn, hh = bh % Hn;
#pragma unroll
        for (int r = 0; r < 16; ++r) {
            const int tr = (r & 3) + 8 * (r >> 2) + 4 * g;
            const int t = qbase + tr;
            float* base = heads + ((size_t)(b * Tn + t)) * Dn + hh * DHn;
            base[lq]      = o0[r] + smem[tr * 64 + lq]
                          + smem[(32 + tr) * 64 + lq] + smem[(64 + tr) * 64 + lq];
            base[32 + lq] = o1[r] + smem[tr * 64 + 32 + lq]
                          + smem[(32 + tr) * 64 + 32 + lq] + smem[(64 + tr) * 64 + 32 + lq];
        }
    }
}

extern "C" void kernel_launch(void* const* d_in, const int* in_sizes, int n_in,
                              void* d_out, int out_size, void* d_ws, size_t ws_size,
                              hipStream_t stream) {
    (void)in_sizes; (void)n_in; (void)out_size; (void)ws_size;
    const float* x  = (const float*)d_in[0];
    const float* Wq = (const float*)d_in[1];
    const float* bq = (const float*)d_in[2];
    const float* Wk = (const float*)d_in[3];
    const float* bk = (const float*)d_in[4];
    const float* Wv = (const float*)d_in[5];
    const float* bv = (const float*)d_in[6];
    // d_in[7] = attn_mask: structurally causal, handled in-kernel.

    float* heads = (float*)d_out;
    float* attn  = heads + (size_t)Bn * Tn * Dn;

    unsigned short* xbf  = (unsigned short*)d_ws;   // [NX] then [3][NW] weights
    unsigned short* qws  = xbf + NX + 3 * (size_t)NW;
    unsigned short* kws  = qws + NX;
    unsigned short* vtws = kws + NX;

    cvt_bf16<<<(NX + 3 * NW) / (256 * 8), 256, 0, stream>>>(x, Wq, Wk, Wv, xbf);
    proj_kernel<<<dim3(64, 12, 3), 256, 0, stream>>>(xbf, xbf + NX, bq, bk, bv,
                                                     qws, kws, vtws);
    attn_fused<<<1536, 256, 0, stream>>>(qws, kws, vtws, heads, attn);
}